// Round 7
// baseline (1086.291 us; speedup 1.0000x reference)
//
#include <hip/hip_runtime.h>

// CrossLayerTranscoder. R7: dec8 K-step split into two m201-style phases:
// {8 ds_read (ks) || 3-gload half-stage -> BAR -> lgkmcnt(0) -> setprio'd
// 16-MFMA -> BAR}, counted vmcnt(6) once per K-step (never 0 mid-loop).
// 3 LDS buffers, depth-2 prefetch, rotation identical to R6 (proven).
// Encoder unchanged (R2 reg-staged + Wd f32->bf16 conversion tail).

#define MT 2048   // B*S
#define HD 1024   // H
#define FD 4096   // F
#define LL 8      // L

typedef __attribute__((ext_vector_type(8))) short short8;
typedef __attribute__((ext_vector_type(4))) float f32x4;
typedef __attribute__((ext_vector_type(4))) unsigned short ushort4v;

typedef const __attribute__((address_space(1))) void GV;
typedef __attribute__((address_space(3))) void LV;

__device__ __forceinline__ void gload16(const void* g, void* l) {
  __builtin_amdgcn_global_load_lds((GV*)g, (LV*)l, 16, 0, 0);
}

#define BAR()                                  \
  do {                                         \
    __builtin_amdgcn_sched_barrier(0);         \
    __builtin_amdgcn_s_barrier();              \
    __builtin_amdgcn_sched_barrier(0);         \
  } while (0)

__device__ __forceinline__ unsigned int f2bf1(float x) {
  unsigned u = __float_as_uint(x);
  return (u + 0x7FFFu + ((u >> 16) & 1u)) >> 16;   // RNE f32->bf16
}

// ---- f32 tile staging (128x64, row stride ld), reg-staged (encoder) -------
__device__ __forceinline__ void load_tile(const float* __restrict__ base, int ld,
                                          float4* r) {
  const int t = threadIdx.x;
#pragma unroll
  for (int i = 0; i < 8; ++i) {
    int idx = t + 256 * i;
    int row = idx >> 4;
    int c4  = idx & 15;
    r[i] = *(const float4*)(base + (size_t)row * ld + c4 * 4);
  }
}

__device__ __forceinline__ void write_tile(char* lds, const float4* r) {
  const int t = threadIdx.x;
#pragma unroll
  for (int i = 0; i < 8; ++i) {
    int idx = t + 256 * i;
    int row = idx >> 4;
    int c4  = idx & 15;
    int off = (row * 128 + c4 * 8) ^ ((row & 7) << 4);
    unsigned lo = f2bf1(r[i].x) | (f2bf1(r[i].y) << 16);
    unsigned hi = f2bf1(r[i].z) | (f2bf1(r[i].w) << 16);
    *(uint2*)(lds + off) = make_uint2(lo, hi);
  }
}

// ---- bf16 tile staging (128x64) for fallback decoder ----------------------
__device__ __forceinline__ void load_tile_bf(const unsigned short* __restrict__ base,
                                             int ld, short8* r) {
  const int t = threadIdx.x;
#pragma unroll
  for (int i = 0; i < 4; ++i) {
    int idx = t + 256 * i;
    int row = idx >> 3;
    int c8  = idx & 7;
    r[i] = *(const short8*)(base + (size_t)row * ld + c8 * 8);
  }
}

__device__ __forceinline__ void write_tile_bf(char* lds, const short8* r) {
  const int t = threadIdx.x;
#pragma unroll
  for (int i = 0; i < 4; ++i) {
    int idx = t + 256 * i;
    int row = idx >> 3;
    int c8  = idx & 7;
    int off = (row * 128 + c8 * 16) ^ ((row & 7) << 4);
    *(short8*)(lds + off) = r[i];
  }
}

// One BK=64 step (enc/fallback): 2 x (read frags + 16 MFMA).
__device__ __forceinline__ void compute_tile(const char* sA, const char* sB,
                                             f32x4 acc[4][4], int wr, int wc,
                                             int l16, int h16) {
#pragma unroll
  for (int ks = 0; ks < 2; ++ks) {
    short8 a[4], b[4];
#pragma unroll
    for (int i = 0; i < 4; ++i) {
      int row = wr * 64 + i * 16 + l16;
      a[i] = *(const short8*)(sA + ((row * 128 + ks * 64 + h16 * 16) ^ ((row & 7) << 4)));
    }
#pragma unroll
    for (int j = 0; j < 4; ++j) {
      int col = wc * 64 + j * 16 + l16;
      b[j] = *(const short8*)(sB + ((col * 128 + ks * 64 + h16 * 16) ^ ((col & 7) << 4)));
    }
#pragma unroll
    for (int i = 0; i < 4; ++i)
#pragma unroll
      for (int j = 0; j < 4; ++j)
        acc[i][j] = __builtin_amdgcn_mfma_f32_16x16x32_bf16(a[i], b[j], acc[i][j], 0, 0, 0);
  }
}

// ---------------- Encoder (+ inline Wd f32->bf16 conversion tail) ----------
__global__ __launch_bounds__(256, 2) void enc_kernel(
    const float* __restrict__ res, const float* __restrict__ We,
    const float* __restrict__ be, const float* __restrict__ thresh,
    float* __restrict__ feats, unsigned short* __restrict__ feats_bf,
    const float* __restrict__ wd_src, unsigned short* __restrict__ wd_dst) {
  __shared__ char sA[128 * 64 * 2];
  __shared__ char sB[128 * 64 * 2];

  const int l  = blockIdx.z;
  const int m0 = blockIdx.y * 128;
  const int f0 = blockIdx.x * 128;

  const float* Abase = res + (size_t)l * MT * HD + (size_t)m0 * HD;
  const float* Bbase = We  + (size_t)l * FD * HD + (size_t)f0 * HD;

  const int t = threadIdx.x;
  const int lane = t & 63, wave = t >> 6;
  const int wr = wave >> 1, wc = wave & 1;
  const int l16 = lane & 15, h16 = lane >> 4;

  f32x4 acc[4][4];
#pragma unroll
  for (int i = 0; i < 4; ++i)
#pragma unroll
    for (int j = 0; j < 4; ++j) acc[i][j] = (f32x4){0.f, 0.f, 0.f, 0.f};

  float4 ra[8], rb[8];
  load_tile(Abase, HD, ra);
  load_tile(Bbase, HD, rb);

  const int NK = HD / 64;
  for (int kt = 0; kt < NK; ++kt) {
    write_tile(sA, ra);
    write_tile(sB, rb);
    __syncthreads();
    if (kt + 1 < NK) {
      load_tile(Abase + (kt + 1) * 64, HD, ra);
      load_tile(Bbase + (kt + 1) * 64, HD, rb);
    }
    compute_tile(sA, sB, acc, wr, wc, l16, h16);
    __syncthreads();
  }

  const float th = thresh[l];
#pragma unroll
  for (int j = 0; j < 4; ++j) {
    int col = f0 + wc * 64 + j * 16 + l16;
    float bev = be[(size_t)l * FD + col];
#pragma unroll
    for (int i = 0; i < 4; ++i) {
      int rbase = m0 + wr * 64 + i * 16 + h16 * 4;
#pragma unroll
      for (int q = 0; q < 4; ++q) {
        float v = acc[i][j][q] + bev;
        float g = (v > th) ? v : 0.f;
        size_t idx = ((size_t)l * MT + rbase + q) * FD + col;
        feats[idx] = g;
        if (feats_bf) feats_bf[idx] = (unsigned short)f2bf1(g);
      }
    }
  }

  // ---- Wd conversion tail: 4096 blocks x 9216 float4 (36/thread) ---------
  if (wd_dst) {
    size_t chunk = ((size_t)blockIdx.z * gridDim.y + blockIdx.y) * gridDim.x
                   + blockIdx.x;                       // 0..4095
    const float4* src = (const float4*)wd_src;
    size_t base = chunk * 9216 + t;
#pragma unroll 4
    for (int i = 0; i < 36; ++i) {
      size_t k = base + (size_t)i * 256;
      float4 v = src[k];
      ushort4v o;
      o.x = (unsigned short)f2bf1(v.x);
      o.y = (unsigned short)f2bf1(v.y);
      o.z = (unsigned short)f2bf1(v.z);
      o.w = (unsigned short)f2bf1(v.w);
      *(ushort4v*)(wd_dst + k * 4) = o;
    }
  }
}

// ---------------- Decoder: deep pipeline, 2 phases per K-step --------------
// LDS per buffer: A 256x64 bf16 (32 KB) + B 128x64 bf16 (16 KB) = 48 KB.
// 3 buffers, depth-2 prefetch. LDS[row][s] = G[row][s ^ (row&7)] via
// pre-swizzled global source slot (linear gload_lds dest).
#define DEC_ABUF 32768
#define DEC_BUFSZ 49152
__global__ __launch_bounds__(512, 2) void dec8(
    const unsigned short* __restrict__ featsbf,
    const unsigned short* __restrict__ wdbf,
    const float* __restrict__ bd, float* __restrict__ recon) {
  __shared__ char lds[3 * DEC_BUFSZ];   // 144 KB -> 1 block/CU

  // XCD-chunk swizzle over 256 blocks (8 XCDs x 32-block chunks, bijective).
  const int flat = (int)(blockIdx.x + 8 * blockIdx.y + 64 * blockIdx.z);
  const int nf = (flat & 7) * 32 + (flat >> 3);
  const int bx = nf & 7;          // h-tile
  const int by = (nf >> 3) & 7;   // m-tile
  const int z  = nf >> 6;         // 0..3 -> lp pair (7-z, z)

  const int m0 = by * 256;
  const int h0 = bx * 128;

  const int t = threadIdx.x;          // 0..511
  const int L = t & 63;
  const int w = t >> 6;               // 8 waves
  const int wm = w >> 1, wn = w & 1;  // 4M x 2N
  const int l16 = L & 15, h16 = L >> 4;

  // staging lane constants: gload i covers rows i*64 + (t>>3); dest slot t&7.
  const int rl   = (t >> 3) & 7;
  const int scol = (t & 7) ^ rl;            // pre-swizzled source 16B-slot
  const int rowl = t >> 3;                  // 0..63
  const size_t laneA = (size_t)(m0 + rowl) * FD + scol * 8;
  const size_t laneB = (size_t)(h0 + rowl) * FD + scol * 8;

  // fragment-read lane constant: slot(ks) = s0 ^ (ks<<2)
  const int s0 = h16 ^ (l16 & 7);

  for (int sub = 0; sub < 2; ++sub) {
    const int lp = sub ? z : 7 - z;
    const int NT = (lp + 1) * 64;     // BK=64 steps over (lp+1) K-panels

    f32x4 acc[4][4];
#pragma unroll
    for (int i = 0; i < 4; ++i)
#pragma unroll
      for (int j = 0; j < 4; ++j) acc[i][j] = (f32x4){0.f, 0.f, 0.f, 0.f};

    auto srcAB = [&](int tt, const unsigned short*& Ab, const unsigned short*& Bb) {
      int l = tt >> 6, kt = tt & 63;
      int p = l * LL - ((l * (l - 1)) >> 1) + (lp - l);
      Ab = featsbf + (size_t)l * MT * FD + kt * 64 + laneA;
      Bb = wdbf + (size_t)p * HD * FD + kt * 64 + laneB;
    };

    auto stage_full = [&](int bi, int tt) {
      const unsigned short *Ab, *Bb;
      srcAB(tt, Ab, Bb);
      char* dA = lds + bi * DEC_BUFSZ + t * 16;
      char* dB = dA + DEC_ABUF;
#pragma unroll
      for (int i = 0; i < 4; ++i)
        gload16(Ab + (size_t)i * 64 * FD, dA + i * 8192);
#pragma unroll
      for (int i = 0; i < 2; ++i)
        gload16(Bb + (size_t)i * 64 * FD, dB + i * 8192);
    };

    auto stage_half = [&](int bi, int tt, int half) {
      const unsigned short *Ab, *Bb;
      srcAB(tt, Ab, Bb);
      char* dA = lds + bi * DEC_BUFSZ + t * 16;
      char* dB = dA + DEC_ABUF;
      if (half == 0) {
        gload16(Ab, dA);
        gload16(Ab + (size_t)64 * FD, dA + 8192);
        gload16(Bb, dB);
      } else {
        gload16(Ab + (size_t)128 * FD, dA + 16384);
        gload16(Ab + (size_t)192 * FD, dA + 24576);
        gload16(Bb + (size_t)64 * FD, dB + 8192);
      }
    };

    // one phase: 8 ds_read + optional 3-gload half-stage -> BAR ->
    // lgkm(0) -> setprio'd 16 MFMA  (trailing ops handled by caller)
    auto phase = [&](int rd, int st, int ks, bool do_stage, int tt2) {
      const char* cA = lds + rd * DEC_BUFSZ;
      const char* cB = cA + DEC_ABUF;
      const int sl = (s0 ^ (ks << 2)) << 4;
      short8 a[4], b[4];
#pragma unroll
      for (int i = 0; i < 4; ++i) {
        int row = wm * 64 + i * 16 + l16;
        a[i] = *(const short8*)(cA + row * 128 + sl);
      }
#pragma unroll
      for (int j = 0; j < 4; ++j) {
        int col = wn * 64 + j * 16 + l16;
        b[j] = *(const short8*)(cB + col * 128 + sl);
      }
      if (do_stage) stage_half(st, tt2, ks);
      BAR();
      asm volatile("s_waitcnt lgkmcnt(0)" ::: "memory");
      __builtin_amdgcn_sched_barrier(0);
      __builtin_amdgcn_s_setprio(1);
#pragma unroll
      for (int i = 0; i < 4; ++i)
#pragma unroll
        for (int j = 0; j < 4; ++j)
          acc[i][j] = __builtin_amdgcn_mfma_f32_16x16x32_bf16(a[i], b[j], acc[i][j], 0, 0, 0);
      __builtin_amdgcn_s_setprio(0);
    };

    // prologue: tiles 0,1 in flight (12 loads); wait tile 0 (6 remain)
    stage_full(0, 0);
    stage_full(1, 1);
    asm volatile("s_waitcnt vmcnt(6)" ::: "memory");
    BAR();

    int rd = 0;
    for (int tt = 0; tt < NT; ++tt) {
      int st = rd + 2;
      if (st >= 3) st -= 3;
      const bool ds = (tt + 2 < NT);
      // phase A (ks=0)
      phase(rd, st, 0, ds, tt + 2);
      BAR();
      // phase B (ks=1)
      phase(rd, st, 1, ds, tt + 2);
      if (ds) {
        asm volatile("s_waitcnt vmcnt(6)" ::: "memory");   // tile tt+1 landed
      } else if (tt + 1 < NT) {
        asm volatile("s_waitcnt vmcnt(0)" ::: "memory");   // drain tail
      }
      BAR();
      if (++rd == 3) rd = 0;
    }

#pragma unroll
    for (int j = 0; j < 4; ++j) {
      int col = h0 + wn * 64 + j * 16 + l16;
      float bsum = 0.f;
      for (int l = 0; l <= lp; ++l) {
        int p = l * LL - ((l * (l - 1)) >> 1) + (lp - l);
        bsum += bd[(size_t)p * HD + col];
      }
#pragma unroll
      for (int i = 0; i < 4; ++i) {
        int rbase = m0 + wm * 64 + i * 16 + h16 * 4;
#pragma unroll
        for (int q = 0; q < 4; ++q)
          recon[((size_t)lp * MT + rbase + q) * HD + col] = acc[i][j][q] + bsum;
      }
    }
  }
}

// ---------------- Fallback decoder (R2 2-phase, reg-staged) ----------------
template <bool ABF16>
__global__ __launch_bounds__(256, 2) void dec_kernel(
    const float* __restrict__ feats_f32, const unsigned short* __restrict__ feats_bf,
    const float* __restrict__ Wd, const float* __restrict__ bd,
    float* __restrict__ recon) {
  __shared__ char sA[128 * 64 * 2];
  __shared__ char sB[128 * 64 * 2];

  const int lp = (LL - 1) - (int)blockIdx.z;
  const int m0 = blockIdx.y * 128;
  const int h0 = blockIdx.x * 128;

  const int t = threadIdx.x;
  const int lane = t & 63, wave = t >> 6;
  const int wr = wave >> 1, wc = wave & 1;
  const int l16 = lane & 15, h16 = lane >> 4;

  f32x4 acc[4][4];
#pragma unroll
  for (int i = 0; i < 4; ++i)
#pragma unroll
    for (int j = 0; j < 4; ++j) acc[i][j] = (f32x4){0.f, 0.f, 0.f, 0.f};

  const int nit = (lp + 1) * (FD / 64);

  auto Abf = [&](int it) -> const unsigned short* {
    int l = it >> 6, kt = it & 63;
    return feats_bf + ((size_t)l * MT + m0) * FD + kt * 64;
  };
  auto Af = [&](int it) -> const float* {
    int l = it >> 6, kt = it & 63;
    return feats_f32 + ((size_t)l * MT + m0) * FD + kt * 64;
  };
  auto Bb = [&](int it) -> const float* {
    int l = it >> 6, kt = it & 63;
    int p = l * LL - l * (l - 1) / 2 + (lp - l);
    return Wd + ((size_t)p * HD + h0) * FD + kt * 64;
  };

  short8 rab[4];
  float4 raf[8];
  float4 rb[8];
  if constexpr (ABF16) load_tile_bf(Abf(0), FD, rab); else load_tile(Af(0), FD, raf);
  load_tile(Bb(0), FD, rb);

  for (int it = 0; it < nit; ++it) {
    if constexpr (ABF16) write_tile_bf(sA, rab); else write_tile(sA, raf);
    write_tile(sB, rb);
    __syncthreads();
    if (it + 1 < nit) {
      if constexpr (ABF16) load_tile_bf(Abf(it + 1), FD, rab);
      else                 load_tile(Af(it + 1), FD, raf);
      load_tile(Bb(it + 1), FD, rb);
    }
    compute_tile(sA, sB, acc, wr, wc, l16, h16);
    __syncthreads();
  }

#pragma unroll
  for (int j = 0; j < 4; ++j) {
    int col = h0 + wc * 64 + j * 16 + l16;
    float bsum = 0.f;
    for (int l = 0; l <= lp; ++l) {
      int p = l * LL - l * (l - 1) / 2 + (lp - l);
      bsum += bd[(size_t)p * HD + col];
    }
#pragma unroll
    for (int i = 0; i < 4; ++i) {
      int rbase = m0 + wr * 64 + i * 16 + h16 * 4;
#pragma unroll
      for (int q = 0; q < 4; ++q) {
        recon[((size_t)lp * MT + rbase + q) * HD + col] = acc[i][j][q] + bsum;
      }
    }
  }
}

extern "C" void kernel_launch(void* const* d_in, const int* in_sizes, int n_in,
                              void* d_out, int out_size, void* d_ws, size_t ws_size,
                              hipStream_t stream) {
  const float* res    = (const float*)d_in[0];
  const float* We     = (const float*)d_in[1];
  const float* be     = (const float*)d_in[2];
  const float* Wd     = (const float*)d_in[3];
  const float* bd     = (const float*)d_in[4];
  const float* thresh = (const float*)d_in[5];

  float* recon = (float*)d_out;                       // L*M*H
  float* feats = recon + (size_t)LL * MT * HD;        // L*M*F

  const size_t featsbf_bytes = (size_t)LL * MT * FD * sizeof(unsigned short); // 128 MiB
  const size_t wdbf_bytes    = (size_t)36 * HD * FD * sizeof(unsigned short); // 288 MiB
  const bool use_bf   = ws_size >= featsbf_bytes;
  const bool use_full = ws_size >= featsbf_bytes + wdbf_bytes;

  unsigned short* feats_bf = use_bf ? (unsigned short*)d_ws : nullptr;
  unsigned short* wd_bf    = (unsigned short*)((char*)d_ws + featsbf_bytes);

  if (use_full) {
    enc_kernel<<<dim3(FD / 128, MT / 128, LL), dim3(256), 0, stream>>>(
        res, We, be, thresh, feats, feats_bf, Wd, wd_bf);
    dec8<<<dim3(HD / 128, MT / 256, 4), dim3(512), 0, stream>>>(
        feats_bf, wd_bf, bd, recon);
  } else {
    enc_kernel<<<dim3(FD / 128, MT / 128, LL), dim3(256), 0, stream>>>(
        res, We, be, thresh, feats, feats_bf, nullptr, nullptr);
    if (use_bf)
      dec_kernel<true><<<dim3(HD / 128, MT / 128, LL), dim3(256), 0, stream>>>(
          feats, feats_bf, Wd, bd, recon);
    else
      dec_kernel<false><<<dim3(HD / 128, MT / 128, LL), dim3(256), 0, stream>>>(
          feats, nullptr, Wd, bd, recon);
  }
}

// Round 8
// 1081.599 us; speedup vs baseline: 1.0043x; 1.0043x over previous
//
#include <hip/hip_runtime.h>

// CrossLayerTranscoder. R8:
//  - decoder dec8: EXACT R6 structure (proven 664 us): BM=256 BN=128 BK=64,
//    512 thr (8 waves 4Mx2N, per-wave 64x64, acc[4][4]), 3 LDS buffers
//    (144 KB), gload_lds with pre-swizzled source, depth-2 prefetch,
//    counted vmcnt(6), raw s_barrier, setprio'd MFMA clusters. Paired lp.
//  - encoder: Wd f32->bf16 conversion as 2 dedicated z-slices (launched
//    first, overlap GEMM blocks across CUs) instead of per-block tail.

#define MT 2048   // B*S
#define HD 1024   // H
#define FD 4096   // F
#define LL 8      // L

typedef __attribute__((ext_vector_type(8))) short short8;
typedef __attribute__((ext_vector_type(4))) float f32x4;
typedef __attribute__((ext_vector_type(4))) unsigned short ushort4v;

typedef const __attribute__((address_space(1))) void GV;
typedef __attribute__((address_space(3))) void LV;

__device__ __forceinline__ void gload16(const void* g, void* l) {
  __builtin_amdgcn_global_load_lds((GV*)g, (LV*)l, 16, 0, 0);
}

#define BAR()                                  \
  do {                                         \
    __builtin_amdgcn_sched_barrier(0);         \
    __builtin_amdgcn_s_barrier();              \
    __builtin_amdgcn_sched_barrier(0);         \
  } while (0)

__device__ __forceinline__ unsigned int f2bf1(float x) {
  unsigned u = __float_as_uint(x);
  return (u + 0x7FFFu + ((u >> 16) & 1u)) >> 16;   // RNE f32->bf16
}

// ---- f32 tile staging (128x64, row stride ld), reg-staged (encoder) -------
__device__ __forceinline__ void load_tile(const float* __restrict__ base, int ld,
                                          float4* r) {
  const int t = threadIdx.x;
#pragma unroll
  for (int i = 0; i < 8; ++i) {
    int idx = t + 256 * i;
    int row = idx >> 4;
    int c4  = idx & 15;
    r[i] = *(const float4*)(base + (size_t)row * ld + c4 * 4);
  }
}

__device__ __forceinline__ void write_tile(char* lds, const float4* r) {
  const int t = threadIdx.x;
#pragma unroll
  for (int i = 0; i < 8; ++i) {
    int idx = t + 256 * i;
    int row = idx >> 4;
    int c4  = idx & 15;
    int off = (row * 128 + c4 * 8) ^ ((row & 7) << 4);
    unsigned lo = f2bf1(r[i].x) | (f2bf1(r[i].y) << 16);
    unsigned hi = f2bf1(r[i].z) | (f2bf1(r[i].w) << 16);
    *(uint2*)(lds + off) = make_uint2(lo, hi);
  }
}

// ---- bf16 tile staging (128x64) for fallback decoder ----------------------
__device__ __forceinline__ void load_tile_bf(const unsigned short* __restrict__ base,
                                             int ld, short8* r) {
  const int t = threadIdx.x;
#pragma unroll
  for (int i = 0; i < 4; ++i) {
    int idx = t + 256 * i;
    int row = idx >> 3;
    int c8  = idx & 7;
    r[i] = *(const short8*)(base + (size_t)row * ld + c8 * 8);
  }
}

__device__ __forceinline__ void write_tile_bf(char* lds, const short8* r) {
  const int t = threadIdx.x;
#pragma unroll
  for (int i = 0; i < 4; ++i) {
    int idx = t + 256 * i;
    int row = idx >> 3;
    int c8  = idx & 7;
    int off = (row * 128 + c8 * 16) ^ ((row & 7) << 4);
    *(short8*)(lds + off) = r[i];
  }
}

// One BK=64 step (enc/fallback): 2 x (read frags + 16 MFMA).
__device__ __forceinline__ void compute_tile(const char* sA, const char* sB,
                                             f32x4 acc[4][4], int wr, int wc,
                                             int l16, int h16) {
#pragma unroll
  for (int ks = 0; ks < 2; ++ks) {
    short8 a[4], b[4];
#pragma unroll
    for (int i = 0; i < 4; ++i) {
      int row = wr * 64 + i * 16 + l16;
      a[i] = *(const short8*)(sA + ((row * 128 + ks * 64 + h16 * 16) ^ ((row & 7) << 4)));
    }
#pragma unroll
    for (int j = 0; j < 4; ++j) {
      int col = wc * 64 + j * 16 + l16;
      b[j] = *(const short8*)(sB + ((col * 128 + ks * 64 + h16 * 16) ^ ((col & 7) << 4)));
    }
#pragma unroll
    for (int i = 0; i < 4; ++i)
#pragma unroll
      for (int j = 0; j < 4; ++j)
        acc[i][j] = __builtin_amdgcn_mfma_f32_16x16x32_bf16(a[i], b[j], acc[i][j], 0, 0, 0);
  }
}

// ---------------- Encoder (+ dedicated Wd-conversion z-slices) -------------
__global__ __launch_bounds__(256, 2) void enc_kernel(
    const float* __restrict__ res, const float* __restrict__ We,
    const float* __restrict__ be, const float* __restrict__ thresh,
    float* __restrict__ feats, unsigned short* __restrict__ feats_bf,
    const float* __restrict__ wd_src, unsigned short* __restrict__ wd_dst,
    int conv_z) {
  __shared__ char sA[128 * 64 * 2];
  __shared__ char sB[128 * 64 * 2];

  if ((int)blockIdx.z < conv_z) {
    // Wd f32 -> bf16: 36*HD*FD = 37,748,736 float4 total.
    // conv_z=2 slices x 16 x 32 = 1024 chunks x (256 thr x 144 float4).
    size_t chunk = ((size_t)blockIdx.z * 16 + blockIdx.y) * 32 + blockIdx.x;
    size_t base = chunk * 36864 + threadIdx.x;
    const float4* src = (const float4*)wd_src;
#pragma unroll 4
    for (int i = 0; i < 144; ++i) {
      size_t k = base + (size_t)i * 256;
      float4 v = src[k];
      ushort4v o;
      o.x = (unsigned short)f2bf1(v.x);
      o.y = (unsigned short)f2bf1(v.y);
      o.z = (unsigned short)f2bf1(v.z);
      o.w = (unsigned short)f2bf1(v.w);
      *(ushort4v*)(wd_dst + k * 4) = o;
    }
    return;
  }

  const int l  = blockIdx.z - conv_z;
  const int m0 = blockIdx.y * 128;
  const int f0 = blockIdx.x * 128;

  const float* Abase = res + (size_t)l * MT * HD + (size_t)m0 * HD;
  const float* Bbase = We  + (size_t)l * FD * HD + (size_t)f0 * HD;

  const int t = threadIdx.x;
  const int lane = t & 63, wave = t >> 6;
  const int wr = wave >> 1, wc = wave & 1;
  const int l16 = lane & 15, h16 = lane >> 4;

  f32x4 acc[4][4];
#pragma unroll
  for (int i = 0; i < 4; ++i)
#pragma unroll
    for (int j = 0; j < 4; ++j) acc[i][j] = (f32x4){0.f, 0.f, 0.f, 0.f};

  float4 ra[8], rb[8];
  load_tile(Abase, HD, ra);
  load_tile(Bbase, HD, rb);

  const int NK = HD / 64;
  for (int kt = 0; kt < NK; ++kt) {
    write_tile(sA, ra);
    write_tile(sB, rb);
    __syncthreads();
    if (kt + 1 < NK) {
      load_tile(Abase + (kt + 1) * 64, HD, ra);
      load_tile(Bbase + (kt + 1) * 64, HD, rb);
    }
    compute_tile(sA, sB, acc, wr, wc, l16, h16);
    __syncthreads();
  }

  const float th = thresh[l];
#pragma unroll
  for (int j = 0; j < 4; ++j) {
    int col = f0 + wc * 64 + j * 16 + l16;
    float bev = be[(size_t)l * FD + col];
#pragma unroll
    for (int i = 0; i < 4; ++i) {
      int rbase = m0 + wr * 64 + i * 16 + h16 * 4;
#pragma unroll
      for (int q = 0; q < 4; ++q) {
        float v = acc[i][j][q] + bev;
        float g = (v > th) ? v : 0.f;
        size_t idx = ((size_t)l * MT + rbase + q) * FD + col;
        feats[idx] = g;
        if (feats_bf) feats_bf[idx] = (unsigned short)f2bf1(g);
      }
    }
  }
}

// ---------------- Decoder: deep pipeline (T3+T4+T5) — exact R6 -------------
// LDS per buffer: A 256x64 bf16 (32 KB) + B 128x64 bf16 (16 KB) = 48 KB.
// 3 buffers, depth-2 prefetch. LDS[row][s] = G[row][s ^ (row&7)] via
// pre-swizzled global source slot (linear gload_lds dest).
#define DEC_ABUF 32768
#define DEC_BUFSZ 49152
__global__ __launch_bounds__(512, 2) void dec8(
    const unsigned short* __restrict__ featsbf,
    const unsigned short* __restrict__ wdbf,
    const float* __restrict__ bd, float* __restrict__ recon) {
  __shared__ char lds[3 * DEC_BUFSZ];   // 144 KB -> 1 block/CU

  // XCD-chunk swizzle over 256 blocks (8 XCDs x 32-block chunks, bijective).
  const int flat = (int)(blockIdx.x + 8 * blockIdx.y + 64 * blockIdx.z);
  const int nf = (flat & 7) * 32 + (flat >> 3);
  const int bx = nf & 7;          // h-tile
  const int by = (nf >> 3) & 7;   // m-tile
  const int z  = nf >> 6;         // 0..3 -> lp pair (7-z, z)

  const int m0 = by * 256;
  const int h0 = bx * 128;

  const int t = threadIdx.x;          // 0..511
  const int L = t & 63;
  const int w = t >> 6;               // 8 waves
  const int wm = w >> 1, wn = w & 1;  // 4M x 2N
  const int l16 = L & 15, h16 = L >> 4;

  // staging lane constants: gload i covers rows i*64 + (t>>3); dest slot t&7.
  const int rl   = (t >> 3) & 7;
  const int scol = (t & 7) ^ rl;            // pre-swizzled source 16B-slot
  const int rowl = t >> 3;                  // 0..63
  const size_t laneA = (size_t)(m0 + rowl) * FD + scol * 8;
  const size_t laneB = (size_t)(h0 + rowl) * FD + scol * 8;

  // fragment-read lane constant: slot(ks) = s0 ^ (ks<<2)
  const int s0 = h16 ^ (l16 & 7);

  for (int sub = 0; sub < 2; ++sub) {
    const int lp = sub ? z : 7 - z;
    const int NT = (lp + 1) * 64;     // BK=64 steps over (lp+1) K-panels

    f32x4 acc[4][4];
#pragma unroll
    for (int i = 0; i < 4; ++i)
#pragma unroll
      for (int j = 0; j < 4; ++j) acc[i][j] = (f32x4){0.f, 0.f, 0.f, 0.f};

    auto stage = [&](int bi, int tt) {
      int l = tt >> 6, kt = tt & 63;
      int p = l * LL - ((l * (l - 1)) >> 1) + (lp - l);
      const unsigned short* Ab = featsbf + (size_t)l * MT * FD + kt * 64 + laneA;
      const unsigned short* Bb = wdbf + (size_t)p * HD * FD + kt * 64 + laneB;
      char* dA = lds + bi * DEC_BUFSZ + t * 16;
      char* dB = dA + DEC_ABUF;
#pragma unroll
      for (int i = 0; i < 4; ++i)
        gload16(Ab + (size_t)i * 64 * FD, dA + i * 8192);
#pragma unroll
      for (int i = 0; i < 2; ++i)
        gload16(Bb + (size_t)i * 64 * FD, dB + i * 8192);
    };

    auto compute = [&](int bi) {
      const char* cA = lds + bi * DEC_BUFSZ;
      const char* cB = cA + DEC_ABUF;
#pragma unroll
      for (int ks = 0; ks < 2; ++ks) {
        const int sl = (s0 ^ (ks << 2)) << 4;
        short8 a[4], b[4];
#pragma unroll
        for (int i = 0; i < 4; ++i) {
          int row = wm * 64 + i * 16 + l16;
          a[i] = *(const short8*)(cA + row * 128 + sl);
        }
#pragma unroll
        for (int j = 0; j < 4; ++j) {
          int col = wn * 64 + j * 16 + l16;
          b[j] = *(const short8*)(cB + col * 128 + sl);
        }
        __builtin_amdgcn_s_setprio(1);
#pragma unroll
        for (int i = 0; i < 4; ++i)
#pragma unroll
          for (int j = 0; j < 4; ++j)
            acc[i][j] = __builtin_amdgcn_mfma_f32_16x16x32_bf16(a[i], b[j], acc[i][j], 0, 0, 0);
        __builtin_amdgcn_s_setprio(0);
      }
    };

    // prologue: tiles 0,1 in flight (12 loads); wait tile 0 (6 remain)
    stage(0, 0);
    stage(1, 1);
    asm volatile("s_waitcnt vmcnt(6)" ::: "memory");
    BAR();

    int rd = 0;
    for (int tt = 0; tt < NT; ++tt) {
      int st = rd + 2;
      if (st >= 3) st -= 3;
      if (tt + 2 < NT) stage(st, tt + 2);   // issue early: spans MFMA phase
      compute(rd);
      if (tt + 2 < NT) {
        asm volatile("s_waitcnt vmcnt(6)" ::: "memory");   // tile tt+1 landed
      } else if (tt + 1 < NT) {
        asm volatile("s_waitcnt vmcnt(0)" ::: "memory");   // drain tail
      }
      BAR();
      if (++rd == 3) rd = 0;
    }

#pragma unroll
    for (int j = 0; j < 4; ++j) {
      int col = h0 + wn * 64 + j * 16 + l16;
      float bsum = 0.f;
      for (int l = 0; l <= lp; ++l) {
        int p = l * LL - ((l * (l - 1)) >> 1) + (lp - l);
        bsum += bd[(size_t)p * HD + col];
      }
#pragma unroll
      for (int i = 0; i < 4; ++i) {
        int rbase = m0 + wm * 64 + i * 16 + h16 * 4;
#pragma unroll
        for (int q = 0; q < 4; ++q)
          recon[((size_t)lp * MT + rbase + q) * HD + col] = acc[i][j][q] + bsum;
      }
    }
  }
}

// ---------------- Fallback decoder (R2 2-phase, reg-staged) ----------------
template <bool ABF16>
__global__ __launch_bounds__(256, 2) void dec_kernel(
    const float* __restrict__ feats_f32, const unsigned short* __restrict__ feats_bf,
    const float* __restrict__ Wd, const float* __restrict__ bd,
    float* __restrict__ recon) {
  __shared__ char sA[128 * 64 * 2];
  __shared__ char sB[128 * 64 * 2];

  const int lp = (LL - 1) - (int)blockIdx.z;
  const int m0 = blockIdx.y * 128;
  const int h0 = blockIdx.x * 128;

  const int t = threadIdx.x;
  const int lane = t & 63, wave = t >> 6;
  const int wr = wave >> 1, wc = wave & 1;
  const int l16 = lane & 15, h16 = lane >> 4;

  f32x4 acc[4][4];
#pragma unroll
  for (int i = 0; i < 4; ++i)
#pragma unroll
    for (int j = 0; j < 4; ++j) acc[i][j] = (f32x4){0.f, 0.f, 0.f, 0.f};

  const int nit = (lp + 1) * (FD / 64);

  auto Abf = [&](int it) -> const unsigned short* {
    int l = it >> 6, kt = it & 63;
    return feats_bf + ((size_t)l * MT + m0) * FD + kt * 64;
  };
  auto Af = [&](int it) -> const float* {
    int l = it >> 6, kt = it & 63;
    return feats_f32 + ((size_t)l * MT + m0) * FD + kt * 64;
  };
  auto Bb = [&](int it) -> const float* {
    int l = it >> 6, kt = it & 63;
    int p = l * LL - l * (l - 1) / 2 + (lp - l);
    return Wd + ((size_t)p * HD + h0) * FD + kt * 64;
  };

  short8 rab[4];
  float4 raf[8];
  float4 rb[8];
  if constexpr (ABF16) load_tile_bf(Abf(0), FD, rab); else load_tile(Af(0), FD, raf);
  load_tile(Bb(0), FD, rb);

  for (int it = 0; it < nit; ++it) {
    if constexpr (ABF16) write_tile_bf(sA, rab); else write_tile(sA, raf);
    write_tile(sB, rb);
    __syncthreads();
    if (it + 1 < nit) {
      if constexpr (ABF16) load_tile_bf(Abf(it + 1), FD, rab);
      else                 load_tile(Af(it + 1), FD, raf);
      load_tile(Bb(it + 1), FD, rb);
    }
    compute_tile(sA, sB, acc, wr, wc, l16, h16);
    __syncthreads();
  }

#pragma unroll
  for (int j = 0; j < 4; ++j) {
    int col = h0 + wc * 64 + j * 16 + l16;
    float bsum = 0.f;
    for (int l = 0; l <= lp; ++l) {
      int p = l * LL - l * (l - 1) / 2 + (lp - l);
      bsum += bd[(size_t)p * HD + col];
    }
#pragma unroll
    for (int i = 0; i < 4; ++i) {
      int rbase = m0 + wr * 64 + i * 16 + h16 * 4;
#pragma unroll
      for (int q = 0; q < 4; ++q) {
        recon[((size_t)lp * MT + rbase + q) * HD + col] = acc[i][j][q] + bsum;
      }
    }
  }
}

extern "C" void kernel_launch(void* const* d_in, const int* in_sizes, int n_in,
                              void* d_out, int out_size, void* d_ws, size_t ws_size,
                              hipStream_t stream) {
  const float* res    = (const float*)d_in[0];
  const float* We     = (const float*)d_in[1];
  const float* be     = (const float*)d_in[2];
  const float* Wd     = (const float*)d_in[3];
  const float* bd     = (const float*)d_in[4];
  const float* thresh = (const float*)d_in[5];

  float* recon = (float*)d_out;                       // L*M*H
  float* feats = recon + (size_t)LL * MT * HD;        // L*M*F

  const size_t featsbf_bytes = (size_t)LL * MT * FD * sizeof(unsigned short); // 128 MiB
  const size_t wdbf_bytes    = (size_t)36 * HD * FD * sizeof(unsigned short); // 288 MiB
  const bool use_bf   = ws_size >= featsbf_bytes;
  const bool use_full = ws_size >= featsbf_bytes + wdbf_bytes;

  unsigned short* feats_bf = use_bf ? (unsigned short*)d_ws : nullptr;
  unsigned short* wd_bf    = (unsigned short*)((char*)d_ws + featsbf_bytes);

  if (use_full) {
    enc_kernel<<<dim3(FD / 128, MT / 128, LL + 2), dim3(256), 0, stream>>>(
        res, We, be, thresh, feats, feats_bf, Wd, wd_bf, 2);
    dec8<<<dim3(HD / 128, MT / 256, 4), dim3(512), 0, stream>>>(
        feats_bf, wd_bf, bd, recon);
  } else {
    enc_kernel<<<dim3(FD / 128, MT / 128, LL), dim3(256), 0, stream>>>(
        res, We, be, thresh, feats, feats_bf, nullptr, nullptr, 0);
    if (use_bf)
      dec_kernel<true><<<dim3(HD / 128, MT / 128, LL), dim3(256), 0, stream>>>(
          feats, feats_bf, Wd, bd, recon);
    else
      dec_kernel<false><<<dim3(HD / 128, MT / 128, LL), dim3(256), 0, stream>>>(
          feats, nullptr, Wd, bd, recon);
  }
}

// Round 9
// 1054.790 us; speedup vs baseline: 1.0299x; 1.0254x over previous
//
#include <hip/hip_runtime.h>

// CrossLayerTranscoder. R9 = R8 with software-pipelined fragment reads in
// dec8: ds_reads issued one half-step (ks) ahead of their MFMA use, so every
// read burst is covered by an independent MFMA cluster (incl. across the
// barrier). Barrier/vmcnt/buffer-rotation skeleton byte-identical to R6/R8.

#define MT 2048   // B*S
#define HD 1024   // H
#define FD 4096   // F
#define LL 8      // L

typedef __attribute__((ext_vector_type(8))) short short8;
typedef __attribute__((ext_vector_type(4))) float f32x4;
typedef __attribute__((ext_vector_type(4))) unsigned short ushort4v;

typedef const __attribute__((address_space(1))) void GV;
typedef __attribute__((address_space(3))) void LV;

__device__ __forceinline__ void gload16(const void* g, void* l) {
  __builtin_amdgcn_global_load_lds((GV*)g, (LV*)l, 16, 0, 0);
}

#define BAR()                                  \
  do {                                         \
    __builtin_amdgcn_sched_barrier(0);         \
    __builtin_amdgcn_s_barrier();              \
    __builtin_amdgcn_sched_barrier(0);         \
  } while (0)

__device__ __forceinline__ unsigned int f2bf1(float x) {
  unsigned u = __float_as_uint(x);
  return (u + 0x7FFFu + ((u >> 16) & 1u)) >> 16;   // RNE f32->bf16
}

// ---- f32 tile staging (128x64, row stride ld), reg-staged (encoder) -------
__device__ __forceinline__ void load_tile(const float* __restrict__ base, int ld,
                                          float4* r) {
  const int t = threadIdx.x;
#pragma unroll
  for (int i = 0; i < 8; ++i) {
    int idx = t + 256 * i;
    int row = idx >> 4;
    int c4  = idx & 15;
    r[i] = *(const float4*)(base + (size_t)row * ld + c4 * 4);
  }
}

__device__ __forceinline__ void write_tile(char* lds, const float4* r) {
  const int t = threadIdx.x;
#pragma unroll
  for (int i = 0; i < 8; ++i) {
    int idx = t + 256 * i;
    int row = idx >> 4;
    int c4  = idx & 15;
    int off = (row * 128 + c4 * 8) ^ ((row & 7) << 4);
    unsigned lo = f2bf1(r[i].x) | (f2bf1(r[i].y) << 16);
    unsigned hi = f2bf1(r[i].z) | (f2bf1(r[i].w) << 16);
    *(uint2*)(lds + off) = make_uint2(lo, hi);
  }
}

// ---- bf16 tile staging (128x64) for fallback decoder ----------------------
__device__ __forceinline__ void load_tile_bf(const unsigned short* __restrict__ base,
                                             int ld, short8* r) {
  const int t = threadIdx.x;
#pragma unroll
  for (int i = 0; i < 4; ++i) {
    int idx = t + 256 * i;
    int row = idx >> 3;
    int c8  = idx & 7;
    r[i] = *(const short8*)(base + (size_t)row * ld + c8 * 8);
  }
}

__device__ __forceinline__ void write_tile_bf(char* lds, const short8* r) {
  const int t = threadIdx.x;
#pragma unroll
  for (int i = 0; i < 4; ++i) {
    int idx = t + 256 * i;
    int row = idx >> 3;
    int c8  = idx & 7;
    int off = (row * 128 + c8 * 16) ^ ((row & 7) << 4);
    *(short8*)(lds + off) = r[i];
  }
}

// One BK=64 step (enc/fallback): 2 x (read frags + 16 MFMA).
__device__ __forceinline__ void compute_tile(const char* sA, const char* sB,
                                             f32x4 acc[4][4], int wr, int wc,
                                             int l16, int h16) {
#pragma unroll
  for (int ks = 0; ks < 2; ++ks) {
    short8 a[4], b[4];
#pragma unroll
    for (int i = 0; i < 4; ++i) {
      int row = wr * 64 + i * 16 + l16;
      a[i] = *(const short8*)(sA + ((row * 128 + ks * 64 + h16 * 16) ^ ((row & 7) << 4)));
    }
#pragma unroll
    for (int j = 0; j < 4; ++j) {
      int col = wc * 64 + j * 16 + l16;
      b[j] = *(const short8*)(sB + ((col * 128 + ks * 64 + h16 * 16) ^ ((col & 7) << 4)));
    }
#pragma unroll
    for (int i = 0; i < 4; ++i)
#pragma unroll
      for (int j = 0; j < 4; ++j)
        acc[i][j] = __builtin_amdgcn_mfma_f32_16x16x32_bf16(a[i], b[j], acc[i][j], 0, 0, 0);
  }
}

// ---------------- Encoder (+ dedicated Wd-conversion z-slices) -------------
__global__ __launch_bounds__(256, 2) void enc_kernel(
    const float* __restrict__ res, const float* __restrict__ We,
    const float* __restrict__ be, const float* __restrict__ thresh,
    float* __restrict__ feats, unsigned short* __restrict__ feats_bf,
    const float* __restrict__ wd_src, unsigned short* __restrict__ wd_dst,
    int conv_z) {
  __shared__ char sA[128 * 64 * 2];
  __shared__ char sB[128 * 64 * 2];

  if ((int)blockIdx.z < conv_z) {
    // Wd f32 -> bf16: 36*HD*FD = 37,748,736 float4 total.
    // conv_z=2 slices x 16 x 32 = 1024 chunks x (256 thr x 144 float4).
    size_t chunk = ((size_t)blockIdx.z * 16 + blockIdx.y) * 32 + blockIdx.x;
    size_t base = chunk * 36864 + threadIdx.x;
    const float4* src = (const float4*)wd_src;
#pragma unroll 4
    for (int i = 0; i < 144; ++i) {
      size_t k = base + (size_t)i * 256;
      float4 v = src[k];
      ushort4v o;
      o.x = (unsigned short)f2bf1(v.x);
      o.y = (unsigned short)f2bf1(v.y);
      o.z = (unsigned short)f2bf1(v.z);
      o.w = (unsigned short)f2bf1(v.w);
      *(ushort4v*)(wd_dst + k * 4) = o;
    }
    return;
  }

  const int l  = blockIdx.z - conv_z;
  const int m0 = blockIdx.y * 128;
  const int f0 = blockIdx.x * 128;

  const float* Abase = res + (size_t)l * MT * HD + (size_t)m0 * HD;
  const float* Bbase = We  + (size_t)l * FD * HD + (size_t)f0 * HD;

  const int t = threadIdx.x;
  const int lane = t & 63, wave = t >> 6;
  const int wr = wave >> 1, wc = wave & 1;
  const int l16 = lane & 15, h16 = lane >> 4;

  f32x4 acc[4][4];
#pragma unroll
  for (int i = 0; i < 4; ++i)
#pragma unroll
    for (int j = 0; j < 4; ++j) acc[i][j] = (f32x4){0.f, 0.f, 0.f, 0.f};

  float4 ra[8], rb[8];
  load_tile(Abase, HD, ra);
  load_tile(Bbase, HD, rb);

  const int NK = HD / 64;
  for (int kt = 0; kt < NK; ++kt) {
    write_tile(sA, ra);
    write_tile(sB, rb);
    __syncthreads();
    if (kt + 1 < NK) {
      load_tile(Abase + (kt + 1) * 64, HD, ra);
      load_tile(Bbase + (kt + 1) * 64, HD, rb);
    }
    compute_tile(sA, sB, acc, wr, wc, l16, h16);
    __syncthreads();
  }

  const float th = thresh[l];
#pragma unroll
  for (int j = 0; j < 4; ++j) {
    int col = f0 + wc * 64 + j * 16 + l16;
    float bev = be[(size_t)l * FD + col];
#pragma unroll
    for (int i = 0; i < 4; ++i) {
      int rbase = m0 + wr * 64 + i * 16 + h16 * 4;
#pragma unroll
      for (int q = 0; q < 4; ++q) {
        float v = acc[i][j][q] + bev;
        float g = (v > th) ? v : 0.f;
        size_t idx = ((size_t)l * MT + rbase + q) * FD + col;
        feats[idx] = g;
        if (feats_bf) feats_bf[idx] = (unsigned short)f2bf1(g);
      }
    }
  }
}

// ---------------- Decoder: deep pipeline + frag software pipeline ----------
// LDS per buffer: A 256x64 bf16 (32 KB) + B 128x64 bf16 (16 KB) = 48 KB.
// 3 buffers, depth-2 prefetch. LDS[row][s] = G[row][s ^ (row&7)] via
// pre-swizzled global source slot (linear gload_lds dest).
#define DEC_ABUF 32768
#define DEC_BUFSZ 49152
__global__ __launch_bounds__(512, 2) void dec8(
    const unsigned short* __restrict__ featsbf,
    const unsigned short* __restrict__ wdbf,
    const float* __restrict__ bd, float* __restrict__ recon) {
  __shared__ char lds[3 * DEC_BUFSZ];   // 144 KB -> 1 block/CU

  // XCD-chunk swizzle over 256 blocks (8 XCDs x 32-block chunks, bijective).
  const int flat = (int)(blockIdx.x + 8 * blockIdx.y + 64 * blockIdx.z);
  const int nf = (flat & 7) * 32 + (flat >> 3);
  const int bx = nf & 7;          // h-tile
  const int by = (nf >> 3) & 7;   // m-tile
  const int z  = nf >> 6;         // 0..3 -> lp pair (7-z, z)

  const int m0 = by * 256;
  const int h0 = bx * 128;

  const int t = threadIdx.x;          // 0..511
  const int L = t & 63;
  const int w = t >> 6;               // 8 waves
  const int wm = w >> 1, wn = w & 1;  // 4M x 2N
  const int l16 = L & 15, h16 = L >> 4;

  // staging lane constants: gload i covers rows i*64 + (t>>3); dest slot t&7.
  const int rl   = (t >> 3) & 7;
  const int scol = (t & 7) ^ rl;            // pre-swizzled source 16B-slot
  const int rowl = t >> 3;                  // 0..63
  const size_t laneA = (size_t)(m0 + rowl) * FD + scol * 8;
  const size_t laneB = (size_t)(h0 + rowl) * FD + scol * 8;

  // fragment-read lane constant: slot(ks) = s0 ^ (ks<<2)
  const int s0 = h16 ^ (l16 & 7);

  for (int sub = 0; sub < 2; ++sub) {
    const int lp = sub ? z : 7 - z;
    const int NT = (lp + 1) * 64;     // BK=64 steps over (lp+1) K-panels

    f32x4 acc[4][4];
#pragma unroll
    for (int i = 0; i < 4; ++i)
#pragma unroll
      for (int j = 0; j < 4; ++j) acc[i][j] = (f32x4){0.f, 0.f, 0.f, 0.f};

    auto stage = [&](int bi, int tt) {
      int l = tt >> 6, kt = tt & 63;
      int p = l * LL - ((l * (l - 1)) >> 1) + (lp - l);
      const unsigned short* Ab = featsbf + (size_t)l * MT * FD + kt * 64 + laneA;
      const unsigned short* Bb = wdbf + (size_t)p * HD * FD + kt * 64 + laneB;
      char* dA = lds + bi * DEC_BUFSZ + t * 16;
      char* dB = dA + DEC_ABUF;
#pragma unroll
      for (int i = 0; i < 4; ++i)
        gload16(Ab + (size_t)i * 64 * FD, dA + i * 8192);
#pragma unroll
      for (int i = 0; i < 2; ++i)
        gload16(Bb + (size_t)i * 64 * FD, dB + i * 8192);
    };

    auto rfrag = [&](int bi, int ks, short8* a, short8* b) {
      const char* cA = lds + bi * DEC_BUFSZ;
      const char* cB = cA + DEC_ABUF;
      const int sl = (s0 ^ (ks << 2)) << 4;
#pragma unroll
      for (int i = 0; i < 4; ++i) {
        int row = wm * 64 + i * 16 + l16;
        a[i] = *(const short8*)(cA + row * 128 + sl);
      }
#pragma unroll
      for (int j = 0; j < 4; ++j) {
        int col = wn * 64 + j * 16 + l16;
        b[j] = *(const short8*)(cB + col * 128 + sl);
      }
    };

    auto cluster = [&](const short8* a, const short8* b) {
      __builtin_amdgcn_s_setprio(1);
#pragma unroll
      for (int i = 0; i < 4; ++i)
#pragma unroll
        for (int j = 0; j < 4; ++j)
          acc[i][j] = __builtin_amdgcn_mfma_f32_16x16x32_bf16(a[i], b[j], acc[i][j], 0, 0, 0);
      __builtin_amdgcn_s_setprio(0);
    };

    // prologue: tiles 0,1 in flight (12 loads); wait tile 0 (6 remain)
    stage(0, 0);
    stage(1, 1);
    asm volatile("s_waitcnt vmcnt(6)" ::: "memory");
    BAR();

    short8 aC[4], bC[4], aN[4], bN[4];
    rfrag(0, 0, aC, bC);              // frags (tile 0, ks=0)

    int rd = 0;
    for (int tt = 0; tt < NT; ++tt) {
      int st = rd + 2;
      if (st >= 3) st -= 3;
      if (tt + 2 < NT) stage(st, tt + 2);   // issue early: spans MFMA phase
      rfrag(rd, 1, aN, bN);                 // reads (tt, ks=1) ...
      cluster(aC, bC);                      // ... covered by MFMA (tt, ks=0)
      if (tt + 2 < NT) {
        asm volatile("s_waitcnt vmcnt(6)" ::: "memory");   // tile tt+1 landed
      } else if (tt + 1 < NT) {
        asm volatile("s_waitcnt vmcnt(0)" ::: "memory");   // drain tail
      }
      BAR();
      int nrd = (rd + 1 == 3) ? 0 : rd + 1;
      if (tt + 1 < NT) rfrag(nrd, 0, aC, bC);  // reads (tt+1, ks=0) ...
      cluster(aN, bN);                         // ... covered by MFMA (tt, ks=1)
      rd = nrd;
    }

#pragma unroll
    for (int j = 0; j < 4; ++j) {
      int col = h0 + wn * 64 + j * 16 + l16;
      float bsum = 0.f;
      for (int l = 0; l <= lp; ++l) {
        int p = l * LL - ((l * (l - 1)) >> 1) + (lp - l);
        bsum += bd[(size_t)p * HD + col];
      }
#pragma unroll
      for (int i = 0; i < 4; ++i) {
        int rbase = m0 + wm * 64 + i * 16 + h16 * 4;
#pragma unroll
        for (int q = 0; q < 4; ++q)
          recon[((size_t)lp * MT + rbase + q) * HD + col] = acc[i][j][q] + bsum;
      }
    }
  }
}

// ---------------- Fallback decoder (R2 2-phase, reg-staged) ----------------
template <bool ABF16>
__global__ __launch_bounds__(256, 2) void dec_kernel(
    const float* __restrict__ feats_f32, const unsigned short* __restrict__ feats_bf,
    const float* __restrict__ Wd, const float* __restrict__ bd,
    float* __restrict__ recon) {
  __shared__ char sA[128 * 64 * 2];
  __shared__ char sB[128 * 64 * 2];

  const int lp = (LL - 1) - (int)blockIdx.z;
  const int m0 = blockIdx.y * 128;
  const int h0 = blockIdx.x * 128;

  const int t = threadIdx.x;
  const int lane = t & 63, wave = t >> 6;
  const int wr = wave >> 1, wc = wave & 1;
  const int l16 = lane & 15, h16 = lane >> 4;

  f32x4 acc[4][4];
#pragma unroll
  for (int i = 0; i < 4; ++i)
#pragma unroll
    for (int j = 0; j < 4; ++j) acc[i][j] = (f32x4){0.f, 0.f, 0.f, 0.f};

  const int nit = (lp + 1) * (FD / 64);

  auto Abf = [&](int it) -> const unsigned short* {
    int l = it >> 6, kt = it & 63;
    return feats_bf + ((size_t)l * MT + m0) * FD + kt * 64;
  };
  auto Af = [&](int it) -> const float* {
    int l = it >> 6, kt = it & 63;
    return feats_f32 + ((size_t)l * MT + m0) * FD + kt * 64;
  };
  auto Bb = [&](int it) -> const float* {
    int l = it >> 6, kt = it & 63;
    int p = l * LL - l * (l - 1) / 2 + (lp - l);
    return Wd + ((size_t)p * HD + h0) * FD + kt * 64;
  };

  short8 rab[4];
  float4 raf[8];
  float4 rb[8];
  if constexpr (ABF16) load_tile_bf(Abf(0), FD, rab); else load_tile(Af(0), FD, raf);
  load_tile(Bb(0), FD, rb);

  for (int it = 0; it < nit; ++it) {
    if constexpr (ABF16) write_tile_bf(sA, rab); else write_tile(sA, raf);
    write_tile(sB, rb);
    __syncthreads();
    if (it + 1 < nit) {
      if constexpr (ABF16) load_tile_bf(Abf(it + 1), FD, rab);
      else                 load_tile(Af(it + 1), FD, raf);
      load_tile(Bb(it + 1), FD, rb);
    }
    compute_tile(sA, sB, acc, wr, wc, l16, h16);
    __syncthreads();
  }

#pragma unroll
  for (int j = 0; j < 4; ++j) {
    int col = h0 + wc * 64 + j * 16 + l16;
    float bsum = 0.f;
    for (int l = 0; l <= lp; ++l) {
      int p = l * LL - l * (l - 1) / 2 + (lp - l);
      bsum += bd[(size_t)p * HD + col];
    }
#pragma unroll
    for (int i = 0; i < 4; ++i) {
      int rbase = m0 + wr * 64 + i * 16 + h16 * 4;
#pragma unroll
      for (int q = 0; q < 4; ++q) {
        recon[((size_t)lp * MT + rbase + q) * HD + col] = acc[i][j][q] + bsum;
      }
    }
  }
}

extern "C" void kernel_launch(void* const* d_in, const int* in_sizes, int n_in,
                              void* d_out, int out_size, void* d_ws, size_t ws_size,
                              hipStream_t stream) {
  const float* res    = (const float*)d_in[0];
  const float* We     = (const float*)d_in[1];
  const float* be     = (const float*)d_in[2];
  const float* Wd     = (const float*)d_in[3];
  const float* bd     = (const float*)d_in[4];
  const float* thresh = (const float*)d_in[5];

  float* recon = (float*)d_out;                       // L*M*H
  float* feats = recon + (size_t)LL * MT * HD;        // L*M*F

  const size_t featsbf_bytes = (size_t)LL * MT * FD * sizeof(unsigned short); // 128 MiB
  const size_t wdbf_bytes    = (size_t)36 * HD * FD * sizeof(unsigned short); // 288 MiB
  const bool use_bf   = ws_size >= featsbf_bytes;
  const bool use_full = ws_size >= featsbf_bytes + wdbf_bytes;

  unsigned short* feats_bf = use_bf ? (unsigned short*)d_ws : nullptr;
  unsigned short* wd_bf    = (unsigned short*)((char*)d_ws + featsbf_bytes);

  if (use_full) {
    enc_kernel<<<dim3(FD / 128, MT / 128, LL + 2), dim3(256), 0, stream>>>(
        res, We, be, thresh, feats, feats_bf, Wd, wd_bf, 2);
    dec8<<<dim3(HD / 128, MT / 256, 4), dim3(512), 0, stream>>>(
        feats_bf, wd_bf, bd, recon);
  } else {
    enc_kernel<<<dim3(FD / 128, MT / 128, LL), dim3(256), 0, stream>>>(
        res, We, be, thresh, feats, feats_bf, nullptr, nullptr, 0);
    if (use_bf)
      dec_kernel<true><<<dim3(HD / 128, MT / 128, LL), dim3(256), 0, stream>>>(
          feats, feats_bf, Wd, bd, recon);
    else
      dec_kernel<false><<<dim3(HD / 128, MT / 128, LL), dim3(256), 0, stream>>>(
          feats, nullptr, Wd, bd, recon);
  }
}

// Round 10
// 1003.259 us; speedup vs baseline: 1.0828x; 1.0514x over previous
//
#include <hip/hip_runtime.h>

// CrossLayerTranscoder. R10:
//  - conv_kernel: one BW-bound pass converting res/We/Wd to bf16 in ws.
//  - enc8: encoder GEMM as a clone of the proven dec8 deep-pipeline skeleton
//    (gload_lds, pre-swizzled source, 3 bufs, depth-2, vmcnt(6), R9 frag
//    pipeline), all-bf16 inputs, epilogue = bias+JumpReLU dual-write.
//    XCD swizzle maps layer l -> XCD l (res_bf[l]=4MB L2-resident).
//  - dec8: byte-identical to R9 (590 us, MfmaUtil 49.9).

#define MT 2048   // B*S
#define HD 1024   // H
#define FD 4096   // F
#define LL 8      // L

typedef __attribute__((ext_vector_type(8))) short short8;
typedef __attribute__((ext_vector_type(4))) float f32x4;
typedef __attribute__((ext_vector_type(4))) unsigned short ushort4v;

typedef const __attribute__((address_space(1))) void GV;
typedef __attribute__((address_space(3))) void LV;

__device__ __forceinline__ void gload16(const void* g, void* l) {
  __builtin_amdgcn_global_load_lds((GV*)g, (LV*)l, 16, 0, 0);
}

#define BAR()                                  \
  do {                                         \
    __builtin_amdgcn_sched_barrier(0);         \
    __builtin_amdgcn_s_barrier();              \
    __builtin_amdgcn_sched_barrier(0);         \
  } while (0)

__device__ __forceinline__ unsigned int f2bf1(float x) {
  unsigned u = __float_as_uint(x);
  return (u + 0x7FFFu + ((u >> 16) & 1u)) >> 16;   // RNE f32->bf16
}

// ---- f32 tile staging (128x64, row stride ld), reg-staged (old encoder) ---
__device__ __forceinline__ void load_tile(const float* __restrict__ base, int ld,
                                          float4* r) {
  const int t = threadIdx.x;
#pragma unroll
  for (int i = 0; i < 8; ++i) {
    int idx = t + 256 * i;
    int row = idx >> 4;
    int c4  = idx & 15;
    r[i] = *(const float4*)(base + (size_t)row * ld + c4 * 4);
  }
}

__device__ __forceinline__ void write_tile(char* lds, const float4* r) {
  const int t = threadIdx.x;
#pragma unroll
  for (int i = 0; i < 8; ++i) {
    int idx = t + 256 * i;
    int row = idx >> 4;
    int c4  = idx & 15;
    int off = (row * 128 + c4 * 8) ^ ((row & 7) << 4);
    unsigned lo = f2bf1(r[i].x) | (f2bf1(r[i].y) << 16);
    unsigned hi = f2bf1(r[i].z) | (f2bf1(r[i].w) << 16);
    *(uint2*)(lds + off) = make_uint2(lo, hi);
  }
}

// ---- bf16 tile staging (128x64) for fallback decoder ----------------------
__device__ __forceinline__ void load_tile_bf(const unsigned short* __restrict__ base,
                                             int ld, short8* r) {
  const int t = threadIdx.x;
#pragma unroll
  for (int i = 0; i < 4; ++i) {
    int idx = t + 256 * i;
    int row = idx >> 3;
    int c8  = idx & 7;
    r[i] = *(const short8*)(base + (size_t)row * ld + c8 * 8);
  }
}

__device__ __forceinline__ void write_tile_bf(char* lds, const short8* r) {
  const int t = threadIdx.x;
#pragma unroll
  for (int i = 0; i < 4; ++i) {
    int idx = t + 256 * i;
    int row = idx >> 3;
    int c8  = idx & 7;
    int off = (row * 128 + c8 * 16) ^ ((row & 7) << 4);
    *(short8*)(lds + off) = r[i];
  }
}

// One BK=64 step (old enc/fallback): 2 x (read frags + 16 MFMA).
__device__ __forceinline__ void compute_tile(const char* sA, const char* sB,
                                             f32x4 acc[4][4], int wr, int wc,
                                             int l16, int h16) {
#pragma unroll
  for (int ks = 0; ks < 2; ++ks) {
    short8 a[4], b[4];
#pragma unroll
    for (int i = 0; i < 4; ++i) {
      int row = wr * 64 + i * 16 + l16;
      a[i] = *(const short8*)(sA + ((row * 128 + ks * 64 + h16 * 16) ^ ((row & 7) << 4)));
    }
#pragma unroll
    for (int j = 0; j < 4; ++j) {
      int col = wc * 64 + j * 16 + l16;
      b[j] = *(const short8*)(sB + ((col * 128 + ks * 64 + h16 * 16) ^ ((col & 7) << 4)));
    }
#pragma unroll
    for (int i = 0; i < 4; ++i)
#pragma unroll
      for (int j = 0; j < 4; ++j)
        acc[i][j] = __builtin_amdgcn_mfma_f32_16x16x32_bf16(a[i], b[j], acc[i][j], 0, 0, 0);
  }
}

// ---------------- conv_kernel: res/We/Wd f32 -> bf16 (BW-bound) ------------
__global__ __launch_bounds__(256) void conv_kernel(
    const float* __restrict__ res, const float* __restrict__ We,
    const float* __restrict__ Wd, unsigned short* __restrict__ res_bf,
    unsigned short* __restrict__ we_bf, unsigned short* __restrict__ wd_bf) {
  const size_t stride = (size_t)gridDim.x * 256;
  const size_t i0 = (size_t)blockIdx.x * 256 + threadIdx.x;
  auto cv = [&](const float* __restrict__ s, unsigned short* __restrict__ d,
                size_t n4) {
    const float4* s4 = (const float4*)s;
    for (size_t k = i0; k < n4; k += stride) {
      float4 v = s4[k];
      ushort4v o;
      o.x = (unsigned short)f2bf1(v.x);
      o.y = (unsigned short)f2bf1(v.y);
      o.z = (unsigned short)f2bf1(v.z);
      o.w = (unsigned short)f2bf1(v.w);
      *(ushort4v*)(d + k * 4) = o;
    }
  };
  cv(res, res_bf, (size_t)LL * MT * HD / 4);
  cv(We,  we_bf,  (size_t)LL * FD * HD / 4);
  cv(Wd,  wd_bf,  (size_t)36 * HD * FD / 4);
}

// ---------------- Old encoder (+ dedicated Wd-conversion z-slices) ---------
__global__ __launch_bounds__(256, 2) void enc_kernel(
    const float* __restrict__ res, const float* __restrict__ We,
    const float* __restrict__ be, const float* __restrict__ thresh,
    float* __restrict__ feats, unsigned short* __restrict__ feats_bf,
    const float* __restrict__ wd_src, unsigned short* __restrict__ wd_dst,
    int conv_z) {
  __shared__ char sA[128 * 64 * 2];
  __shared__ char sB[128 * 64 * 2];

  if ((int)blockIdx.z < conv_z) {
    size_t chunk = ((size_t)blockIdx.z * 16 + blockIdx.y) * 32 + blockIdx.x;
    size_t base = chunk * 36864 + threadIdx.x;
    const float4* src = (const float4*)wd_src;
#pragma unroll 4
    for (int i = 0; i < 144; ++i) {
      size_t k = base + (size_t)i * 256;
      float4 v = src[k];
      ushort4v o;
      o.x = (unsigned short)f2bf1(v.x);
      o.y = (unsigned short)f2bf1(v.y);
      o.z = (unsigned short)f2bf1(v.z);
      o.w = (unsigned short)f2bf1(v.w);
      *(ushort4v*)(wd_dst + k * 4) = o;
    }
    return;
  }

  const int l  = blockIdx.z - conv_z;
  const int m0 = blockIdx.y * 128;
  const int f0 = blockIdx.x * 128;

  const float* Abase = res + (size_t)l * MT * HD + (size_t)m0 * HD;
  const float* Bbase = We  + (size_t)l * FD * HD + (size_t)f0 * HD;

  const int t = threadIdx.x;
  const int lane = t & 63, wave = t >> 6;
  const int wr = wave >> 1, wc = wave & 1;
  const int l16 = lane & 15, h16 = lane >> 4;

  f32x4 acc[4][4];
#pragma unroll
  for (int i = 0; i < 4; ++i)
#pragma unroll
    for (int j = 0; j < 4; ++j) acc[i][j] = (f32x4){0.f, 0.f, 0.f, 0.f};

  float4 ra[8], rb[8];
  load_tile(Abase, HD, ra);
  load_tile(Bbase, HD, rb);

  const int NK = HD / 64;
  for (int kt = 0; kt < NK; ++kt) {
    write_tile(sA, ra);
    write_tile(sB, rb);
    __syncthreads();
    if (kt + 1 < NK) {
      load_tile(Abase + (kt + 1) * 64, HD, ra);
      load_tile(Bbase + (kt + 1) * 64, HD, rb);
    }
    compute_tile(sA, sB, acc, wr, wc, l16, h16);
    __syncthreads();
  }

  const float th = thresh[l];
#pragma unroll
  for (int j = 0; j < 4; ++j) {
    int col = f0 + wc * 64 + j * 16 + l16;
    float bev = be[(size_t)l * FD + col];
#pragma unroll
    for (int i = 0; i < 4; ++i) {
      int rbase = m0 + wr * 64 + i * 16 + h16 * 4;
#pragma unroll
      for (int q = 0; q < 4; ++q) {
        float v = acc[i][j][q] + bev;
        float g = (v > th) ? v : 0.f;
        size_t idx = ((size_t)l * MT + rbase + q) * FD + col;
        feats[idx] = g;
        if (feats_bf) feats_bf[idx] = (unsigned short)f2bf1(g);
      }
    }
  }
}

// ---------------- enc8: dec8-skeleton encoder GEMM -------------------------
// A = res_bf[l] (M x K=1024), B = we_bf[l] (F x K), both K-major bf16.
// BM=256 BN=128 BK=64, 3 LDS buffers, depth-2, vmcnt(6), R9 frag pipeline.
#define DEC_ABUF 32768
#define DEC_BUFSZ 49152
__global__ __launch_bounds__(512, 2) void enc8(
    const unsigned short* __restrict__ resbf,
    const unsigned short* __restrict__ webf,
    const float* __restrict__ be, const float* __restrict__ thresh,
    float* __restrict__ feats, unsigned short* __restrict__ feats_bf) {
  __shared__ char lds[3 * DEC_BUFSZ];

  // XCD-chunk swizzle over 2048 blocks (8 XCDs x 256 chunks): XCD x = layer x.
  const int flat = (int)(blockIdx.x + 32 * blockIdx.y + 256 * blockIdx.z);
  const int nf = (flat & 7) * 256 + (flat >> 3);
  const int bx = nf & 31;          // f-tile 0..31
  const int by = (nf >> 5) & 7;    // m-tile 0..7
  const int l  = nf >> 8;          // layer 0..7

  const int m0 = by * 256;
  const int f0 = bx * 128;

  const int t = threadIdx.x;          // 0..511
  const int L = t & 63;
  const int w = t >> 6;               // 8 waves
  const int wm = w >> 1, wn = w & 1;  // 4M x 2N
  const int l16 = L & 15, h16 = L >> 4;

  const int rl   = (t >> 3) & 7;
  const int scol = (t & 7) ^ rl;            // pre-swizzled source 16B-slot
  const int rowl = t >> 3;                  // 0..63
  const unsigned short* Abase = resbf + (size_t)l * MT * HD;
  const unsigned short* Bbase = webf + (size_t)l * FD * HD;
  const size_t laneA = (size_t)(m0 + rowl) * HD + scol * 8;
  const size_t laneB = (size_t)(f0 + rowl) * HD + scol * 8;

  const int s0 = h16 ^ (l16 & 7);
  const int NT = HD / 64;             // 16

  f32x4 acc[4][4];
#pragma unroll
  for (int i = 0; i < 4; ++i)
#pragma unroll
    for (int j = 0; j < 4; ++j) acc[i][j] = (f32x4){0.f, 0.f, 0.f, 0.f};

  auto stage = [&](int bi, int tt) {
    const unsigned short* Ab = Abase + (size_t)tt * 64 + laneA;
    const unsigned short* Bb = Bbase + (size_t)tt * 64 + laneB;
    char* dA = lds + bi * DEC_BUFSZ + t * 16;
    char* dB = dA + DEC_ABUF;
#pragma unroll
    for (int i = 0; i < 4; ++i)
      gload16(Ab + (size_t)i * 64 * HD, dA + i * 8192);
#pragma unroll
    for (int i = 0; i < 2; ++i)
      gload16(Bb + (size_t)i * 64 * HD, dB + i * 8192);
  };

  auto rfrag = [&](int bi, int ks, short8* a, short8* b) {
    const char* cA = lds + bi * DEC_BUFSZ;
    const char* cB = cA + DEC_ABUF;
    const int sl = (s0 ^ (ks << 2)) << 4;
#pragma unroll
    for (int i = 0; i < 4; ++i) {
      int row = wm * 64 + i * 16 + l16;
      a[i] = *(const short8*)(cA + row * 128 + sl);
    }
#pragma unroll
    for (int j = 0; j < 4; ++j) {
      int col = wn * 64 + j * 16 + l16;
      b[j] = *(const short8*)(cB + col * 128 + sl);
    }
  };

  auto cluster = [&](const short8* a, const short8* b) {
    __builtin_amdgcn_s_setprio(1);
#pragma unroll
    for (int i = 0; i < 4; ++i)
#pragma unroll
      for (int j = 0; j < 4; ++j)
        acc[i][j] = __builtin_amdgcn_mfma_f32_16x16x32_bf16(a[i], b[j], acc[i][j], 0, 0, 0);
    __builtin_amdgcn_s_setprio(0);
  };

  stage(0, 0);
  stage(1, 1);
  asm volatile("s_waitcnt vmcnt(6)" ::: "memory");
  BAR();

  short8 aC[4], bC[4], aN[4], bN[4];
  rfrag(0, 0, aC, bC);

  int rd = 0;
  for (int tt = 0; tt < NT; ++tt) {
    int st = rd + 2;
    if (st >= 3) st -= 3;
    if (tt + 2 < NT) stage(st, tt + 2);
    rfrag(rd, 1, aN, bN);
    cluster(aC, bC);
    if (tt + 2 < NT) {
      asm volatile("s_waitcnt vmcnt(6)" ::: "memory");
    } else if (tt + 1 < NT) {
      asm volatile("s_waitcnt vmcnt(0)" ::: "memory");
    }
    BAR();
    int nrd = (rd + 1 == 3) ? 0 : rd + 1;
    if (tt + 1 < NT) rfrag(nrd, 0, aC, bC);
    cluster(aN, bN);
    rd = nrd;
  }

  const float th = thresh[l];
#pragma unroll
  for (int j = 0; j < 4; ++j) {
    int col = f0 + wn * 64 + j * 16 + l16;
    float bev = be[(size_t)l * FD + col];
#pragma unroll
    for (int i = 0; i < 4; ++i) {
      int rbase = m0 + wm * 64 + i * 16 + h16 * 4;
#pragma unroll
      for (int q = 0; q < 4; ++q) {
        float v = acc[i][j][q] + bev;
        float g = (v > th) ? v : 0.f;
        size_t idx = ((size_t)l * MT + rbase + q) * FD + col;
        feats[idx] = g;
        feats_bf[idx] = (unsigned short)f2bf1(g);
      }
    }
  }
}

// ---------------- Decoder: deep pipeline + frag software pipeline (R9) -----
__global__ __launch_bounds__(512, 2) void dec8(
    const unsigned short* __restrict__ featsbf,
    const unsigned short* __restrict__ wdbf,
    const float* __restrict__ bd, float* __restrict__ recon) {
  __shared__ char lds[3 * DEC_BUFSZ];   // 144 KB -> 1 block/CU

  const int flat = (int)(blockIdx.x + 8 * blockIdx.y + 64 * blockIdx.z);
  const int nf = (flat & 7) * 32 + (flat >> 3);
  const int bx = nf & 7;          // h-tile
  const int by = (nf >> 3) & 7;   // m-tile
  const int z  = nf >> 6;         // 0..3 -> lp pair (7-z, z)

  const int m0 = by * 256;
  const int h0 = bx * 128;

  const int t = threadIdx.x;          // 0..511
  const int L = t & 63;
  const int w = t >> 6;               // 8 waves
  const int wm = w >> 1, wn = w & 1;  // 4M x 2N
  const int l16 = L & 15, h16 = L >> 4;

  const int rl   = (t >> 3) & 7;
  const int scol = (t & 7) ^ rl;            // pre-swizzled source 16B-slot
  const int rowl = t >> 3;                  // 0..63
  const size_t laneA = (size_t)(m0 + rowl) * FD + scol * 8;
  const size_t laneB = (size_t)(h0 + rowl) * FD + scol * 8;

  const int s0 = h16 ^ (l16 & 7);

  for (int sub = 0; sub < 2; ++sub) {
    const int lp = sub ? z : 7 - z;
    const int NT = (lp + 1) * 64;

    f32x4 acc[4][4];
#pragma unroll
    for (int i = 0; i < 4; ++i)
#pragma unroll
      for (int j = 0; j < 4; ++j) acc[i][j] = (f32x4){0.f, 0.f, 0.f, 0.f};

    auto stage = [&](int bi, int tt) {
      int l = tt >> 6, kt = tt & 63;
      int p = l * LL - ((l * (l - 1)) >> 1) + (lp - l);
      const unsigned short* Ab = featsbf + (size_t)l * MT * FD + kt * 64 + laneA;
      const unsigned short* Bb = wdbf + (size_t)p * HD * FD + kt * 64 + laneB;
      char* dA = lds + bi * DEC_BUFSZ + t * 16;
      char* dB = dA + DEC_ABUF;
#pragma unroll
      for (int i = 0; i < 4; ++i)
        gload16(Ab + (size_t)i * 64 * FD, dA + i * 8192);
#pragma unroll
      for (int i = 0; i < 2; ++i)
        gload16(Bb + (size_t)i * 64 * FD, dB + i * 8192);
    };

    auto rfrag = [&](int bi, int ks, short8* a, short8* b) {
      const char* cA = lds + bi * DEC_BUFSZ;
      const char* cB = cA + DEC_ABUF;
      const int sl = (s0 ^ (ks << 2)) << 4;
#pragma unroll
      for (int i = 0; i < 4; ++i) {
        int row = wm * 64 + i * 16 + l16;
        a[i] = *(const short8*)(cA + row * 128 + sl);
      }
#pragma unroll
      for (int j = 0; j < 4; ++j) {
        int col = wn * 64 + j * 16 + l16;
        b[j] = *(const short8*)(cB + col * 128 + sl);
      }
    };

    auto cluster = [&](const short8* a, const short8* b) {
      __builtin_amdgcn_s_setprio(1);
#pragma unroll
      for (int i = 0; i < 4; ++i)
#pragma unroll
        for (int j = 0; j < 4; ++j)
          acc[i][j] = __builtin_amdgcn_mfma_f32_16x16x32_bf16(a[i], b[j], acc[i][j], 0, 0, 0);
      __builtin_amdgcn_s_setprio(0);
    };

    stage(0, 0);
    stage(1, 1);
    asm volatile("s_waitcnt vmcnt(6)" ::: "memory");
    BAR();

    short8 aC[4], bC[4], aN[4], bN[4];
    rfrag(0, 0, aC, bC);

    int rd = 0;
    for (int tt = 0; tt < NT; ++tt) {
      int st = rd + 2;
      if (st >= 3) st -= 3;
      if (tt + 2 < NT) stage(st, tt + 2);
      rfrag(rd, 1, aN, bN);
      cluster(aC, bC);
      if (tt + 2 < NT) {
        asm volatile("s_waitcnt vmcnt(6)" ::: "memory");
      } else if (tt + 1 < NT) {
        asm volatile("s_waitcnt vmcnt(0)" ::: "memory");
      }
      BAR();
      int nrd = (rd + 1 == 3) ? 0 : rd + 1;
      if (tt + 1 < NT) rfrag(nrd, 0, aC, bC);
      cluster(aN, bN);
      rd = nrd;
    }

#pragma unroll
    for (int j = 0; j < 4; ++j) {
      int col = h0 + wn * 64 + j * 16 + l16;
      float bsum = 0.f;
      for (int l = 0; l <= lp; ++l) {
        int p = l * LL - ((l * (l - 1)) >> 1) + (lp - l);
        bsum += bd[(size_t)p * HD + col];
      }
#pragma unroll
      for (int i = 0; i < 4; ++i) {
        int rbase = m0 + wm * 64 + i * 16 + h16 * 4;
#pragma unroll
        for (int q = 0; q < 4; ++q)
          recon[((size_t)lp * MT + rbase + q) * HD + col] = acc[i][j][q] + bsum;
      }
    }
  }
}

// ---------------- Fallback decoder (R2 2-phase, reg-staged) ----------------
template <bool ABF16>
__global__ __launch_bounds__(256, 2) void dec_kernel(
    const float* __restrict__ feats_f32, const unsigned short* __restrict__ feats_bf,
    const float* __restrict__ Wd, const float* __restrict__ bd,
    float* __restrict__ recon) {
  __shared__ char sA[128 * 64 * 2];
  __shared__ char sB[128 * 64 * 2];

  const int lp = (LL - 1) - (int)blockIdx.z;
  const int m0 = blockIdx.y * 128;
  const int h0 = blockIdx.x * 128;

  const int t = threadIdx.x;
  const int lane = t & 63, wave = t >> 6;
  const int wr = wave >> 1, wc = wave & 1;
  const int l16 = lane & 15, h16 = lane >> 4;

  f32x4 acc[4][4];
#pragma unroll
  for (int i = 0; i < 4; ++i)
#pragma unroll
    for (int j = 0; j < 4; ++j) acc[i][j] = (f32x4){0.f, 0.f, 0.f, 0.f};

  const int nit = (lp + 1) * (FD / 64);

  auto Abf = [&](int it) -> const unsigned short* {
    int l = it >> 6, kt = it & 63;
    return feats_bf + ((size_t)l * MT + m0) * FD + kt * 64;
  };
  auto Af = [&](int it) -> const float* {
    int l = it >> 6, kt = it & 63;
    return feats_f32 + ((size_t)l * MT + m0) * FD + kt * 64;
  };
  auto Bb = [&](int it) -> const float* {
    int l = it >> 6, kt = it & 63;
    int p = l * LL - l * (l - 1) / 2 + (lp - l);
    return Wd + ((size_t)p * HD + h0) * FD + kt * 64;
  };

  short8 rab[4];
  float4 raf[8];
  float4 rb[8];
  if constexpr (ABF16) load_tile_bf(Abf(0), FD, rab); else load_tile(Af(0), FD, raf);
  load_tile(Bb(0), FD, rb);

  for (int it = 0; it < nit; ++it) {
    if constexpr (ABF16) write_tile_bf(sA, rab); else write_tile(sA, raf);
    write_tile(sB, rb);
    __syncthreads();
    if (it + 1 < nit) {
      if constexpr (ABF16) load_tile_bf(Abf(it + 1), FD, rab);
      else                 load_tile(Af(it + 1), FD, raf);
      load_tile(Bb(it + 1), FD, rb);
    }
    compute_tile(sA, sB, acc, wr, wc, l16, h16);
    __syncthreads();
  }

#pragma unroll
  for (int j = 0; j < 4; ++j) {
    int col = h0 + wc * 64 + j * 16 + l16;
    float bsum = 0.f;
    for (int l = 0; l <= lp; ++l) {
      int p = l * LL - l * (l - 1) / 2 + (lp - l);
      bsum += bd[(size_t)p * HD + col];
    }
#pragma unroll
    for (int i = 0; i < 4; ++i) {
      int rbase = m0 + wr * 64 + i * 16 + h16 * 4;
#pragma unroll
      for (int q = 0; q < 4; ++q) {
        recon[((size_t)lp * MT + rbase + q) * HD + col] = acc[i][j][q] + bsum;
      }
    }
  }
}

extern "C" void kernel_launch(void* const* d_in, const int* in_sizes, int n_in,
                              void* d_out, int out_size, void* d_ws, size_t ws_size,
                              hipStream_t stream) {
  const float* res    = (const float*)d_in[0];
  const float* We     = (const float*)d_in[1];
  const float* be     = (const float*)d_in[2];
  const float* Wd     = (const float*)d_in[3];
  const float* bd     = (const float*)d_in[4];
  const float* thresh = (const float*)d_in[5];

  float* recon = (float*)d_out;                       // L*M*H
  float* feats = recon + (size_t)LL * MT * HD;        // L*M*F

  const size_t featsbf_b = (size_t)LL * MT * FD * 2;  // 128 MiB
  const size_t wdbf_b    = (size_t)36 * HD * FD * 2;  // 288 MiB
  const size_t resbf_b   = (size_t)LL * MT * HD * 2;  //  32 MiB
  const size_t webf_b    = (size_t)LL * FD * HD * 2;  //  64 MiB

  const bool use_bf   = ws_size >= featsbf_b;
  const bool use_full = ws_size >= featsbf_b + wdbf_b;
  const bool use_v3   = ws_size >= featsbf_b + wdbf_b + resbf_b + webf_b; // 512 MiB

  unsigned short* feats_bf = (unsigned short*)d_ws;
  unsigned short* wd_bf    = (unsigned short*)((char*)d_ws + featsbf_b);
  unsigned short* res_bf   = (unsigned short*)((char*)d_ws + featsbf_b + wdbf_b);
  unsigned short* we_bf    = (unsigned short*)((char*)d_ws + featsbf_b + wdbf_b + resbf_b);

  if (use_v3) {
    conv_kernel<<<dim3(2048), dim3(256), 0, stream>>>(res, We, Wd, res_bf, we_bf, wd_bf);
    enc8<<<dim3(32, 8, 8), dim3(512), 0, stream>>>(res_bf, we_bf, be, thresh,
                                                   feats, feats_bf);
    dec8<<<dim3(8, 8, 4), dim3(512), 0, stream>>>(feats_bf, wd_bf, bd, recon);
  } else if (use_full) {
    enc_kernel<<<dim3(32, 16, LL + 2), dim3(256), 0, stream>>>(
        res, We, be, thresh, feats, feats_bf, Wd, wd_bf, 2);
    dec8<<<dim3(8, 8, 4), dim3(512), 0, stream>>>(feats_bf, wd_bf, bd, recon);
  } else if (use_bf) {
    enc_kernel<<<dim3(32, 16, LL), dim3(256), 0, stream>>>(
        res, We, be, thresh, feats, feats_bf, nullptr, nullptr, 0);
    dec_kernel<true><<<dim3(8, 16, LL), dim3(256), 0, stream>>>(
        feats, feats_bf, Wd, bd, recon);
  } else {
    enc_kernel<<<dim3(32, 16, LL), dim3(256), 0, stream>>>(
        res, We, be, thresh, feats, nullptr, nullptr, nullptr, 0);
    dec_kernel<false><<<dim3(8, 16, LL), dim3(256), 0, stream>>>(
        feats, nullptr, Wd, bd, recon);
  }
}